// Round 4
// baseline (1459.735 us; speedup 1.0000x reference)
//
#include <hip/hip_runtime.h>
#include <math.h>

// SNNEventModel: causal conv (K=8, L2-normalized filters) -> LIF scan.
// B=64, 2 input chans, 16 filters each => 32 output channels, L=16384.
// Outputs (concat flat): v[64*32*L], z[64*32*L], s[64*32*L], logits[64*L].
//
// Chunked scan: CHUNK=256 main steps, WARM=192 warm-up steps from v=0;
// spikes reset state to exactly 0.0 (bitwise absorption), and alpha^192
// ~= 1e-28 kills any residual initial-state error.
//
// ALL trajectory arithmetic in FLOAT64 (conv, alpha chain, scan), f32 only
// at the output casts. Rounds 2/3 failed with a BIT-IDENTICAL single
// spike-flip (z err 2.6797 ~= 15*alpha*0.25 cascade) insensitive to scan
// op order and WARM — a knife-edge v_pre one ulp from THR where my f32
// conv order differed from the np reference's. At f64 precision the
// order-dependent error is ~1e-16 and the flip probability over 33.5M
// steps is ~3e-8: the f64 trajectory IS the reference trajectory.

#define LSEQ 16384
#define KW 8
#define NB 64
#define CHUNK 256
#define WARM 192

typedef float v4f __attribute__((ext_vector_type(4)));

__global__ __launch_bounds__(256, 2)
void snn_kernel(const float* __restrict__ x,
                const float* __restrict__ wa,
                const float* __restrict__ wb,
                const float* __restrict__ rta,
                const float* __restrict__ rtb,
                float* __restrict__ out)
{
    __shared__ double s_wn[32][KW];
    __shared__ double s_alpha[32];
    __shared__ double s_oma[32];

    const int tid = threadIdx.x;
    if (tid < 32) {
        const float* w = (tid < 16) ? (wa + tid * KW) : (wb + (tid - 16) * KW);
        double ss = 0.0;
        #pragma unroll
        for (int k = 0; k < KW; ++k) { double wv = (double)w[k]; ss = fma(wv, wv, ss); }
        double norm = fmax(sqrt(ss), 1e-8);          // clip(sqrt(sum w^2), 1e-8)
        #pragma unroll
        for (int k = 0; k < KW; ++k) s_wn[tid][k] = (double)w[k] / norm;

        double rt = (double)((tid < 16) ? rta[tid] : rtb[tid - 16]);
        // softplus(x) = max(x,0) + log1p(exp(-|x|))  (f64)
        double sp    = fmax(rt, 0.0) + log1p(exp(-fabs(rt)));
        double tau   = sp + 1e-4;
        double alpha = exp(-1.0 / tau);              // DT = 1.0
        s_alpha[tid] = alpha;
        s_oma[tid]   = 1.0 - alpha;
    }
    __syncthreads();

    // lane mapping: f2 = lane&31 (output channel), bsub = lane>>5.
    // All lanes of a wave share one chunk (zero divergence); lanes 0..31 /
    // 32..63 hold all 32 channels of one batch element -> shfl_xor logits max.
    const int f2     = tid & 31;
    const int bsub   = (tid >> 5) & 1;
    const int wchunk = tid >> 6;            // 0..3  (4 waves per block)
    const int bpair  = blockIdx.x & 31;     // 32 batch pairs
    const int cgroup = blockIdx.x >> 5;     // 16 chunk groups
    const int b      = bpair * 2 + bsub;
    const int chunk  = cgroup * 4 + wchunk; // 0..63
    const int chan   = f2 >> 4;

    double wn[KW];
    #pragma unroll
    for (int k = 0; k < KW; ++k) wn[k] = s_wn[f2][k];
    const double alpha = s_alpha[f2];
    const double oma   = s_oma[f2];

    const float* xp = x + ((size_t)b * 2 + chan) * LSEQ;

    const int main_start = chunk * CHUNK;
    const int t_begin    = (chunk == 0) ? 0 : (main_start - WARM);
    const int t_end      = main_start + CHUNK;

    const size_t NCH = (size_t)NB * 32 * LSEQ;  // 33,554,432 elements
    const size_t row = (size_t)(b * 32 + f2) * LSEQ;
    float* vout = out + row;
    float* zout = out + NCH + row;
    float* sout = out + 2 * NCH + row;
    float* lout = out + 3 * NCH + (size_t)b * LSEQ;

    // sliding x window (f64): prev[j] = x[t-8+j]
    double prev[8];
    if (t_begin >= 8) {
        v4f p0 = *reinterpret_cast<const v4f*>(xp + t_begin - 8);
        v4f p1 = *reinterpret_cast<const v4f*>(xp + t_begin - 4);
        prev[0]=(double)p0[0]; prev[1]=(double)p0[1]; prev[2]=(double)p0[2]; prev[3]=(double)p0[3];
        prev[4]=(double)p1[0]; prev[5]=(double)p1[1]; prev[6]=(double)p1[2]; prev[7]=(double)p1[3];
    } else {
        #pragma unroll
        for (int j = 0; j < 8; ++j) prev[j] = 0.0;  // causal left pad
    }

    double v = 0.0;
    float vbuf[16], zbuf[16], sbuf[16], lbuf[16];

    for (int t = t_begin; t < t_end; t += 16) {
        v4f c0 = *reinterpret_cast<const v4f*>(xp + t);
        v4f c1 = *reinterpret_cast<const v4f*>(xp + t + 4);
        v4f c2 = *reinterpret_cast<const v4f*>(xp + t + 8);
        v4f c3 = *reinterpret_cast<const v4f*>(xp + t + 12);
        double cur[16] = { (double)c0[0],(double)c0[1],(double)c0[2],(double)c0[3],
                           (double)c1[0],(double)c1[1],(double)c1[2],(double)c1[3],
                           (double)c2[0],(double)c2[1],(double)c2[2],(double)c2[3],
                           (double)c3[0],(double)c3[1],(double)c3[2],(double)c3[3] };
        const bool is_main = (t >= main_start);   // uniform across wave

        #pragma unroll
        for (int p = 0; p < 16; ++p) {
            // I[t+p] = sum_k wn[k] * x[t+p-7+k]   (f64)
            double I = 0.0;
            #pragma unroll
            for (int k = 0; k < KW; ++k) {
                const int idx = p + k - 7;        // compile-time constant
                const double xv = (idx < 0) ? prev[8 + idx] : cur[idx];
                I = fma(wn[k], xv, I);
            }
            const double v_pre = fma(alpha, v, oma * I);
            const double z     = 15.0 * (v_pre - 0.25);
            const bool   spike = (v_pre >= 0.25);
            v = spike ? 0.0 : v_pre;              // v_pre*(1-s_hard), exact
            vbuf[p] = (float)v_pre;
            zbuf[p] = (float)z;
            sbuf[p] = spike ? 1.f : 0.f;          // straight-through fwd == s_hard

            // logits: max over 32 channels. f64->f32 cast is monotone, so
            // max of casts == cast of max (exact).
            float zm = zbuf[p];
            zm = fmaxf(zm, __shfl_xor(zm, 1));
            zm = fmaxf(zm, __shfl_xor(zm, 2));
            zm = fmaxf(zm, __shfl_xor(zm, 4));
            zm = fmaxf(zm, __shfl_xor(zm, 8));
            zm = fmaxf(zm, __shfl_xor(zm, 16));
            lbuf[p] = zm;
        }

        if (is_main) {
            // one full 64B line per array per lane, 4 back-to-back stores each
            #pragma unroll
            for (int q = 0; q < 4; ++q) {
                v4f v4 = { vbuf[4*q], vbuf[4*q+1], vbuf[4*q+2], vbuf[4*q+3] };
                __builtin_nontemporal_store(v4, (v4f*)(vout + t + 4*q));
            }
            #pragma unroll
            for (int q = 0; q < 4; ++q) {
                v4f z4 = { zbuf[4*q], zbuf[4*q+1], zbuf[4*q+2], zbuf[4*q+3] };
                __builtin_nontemporal_store(z4, (v4f*)(zout + t + 4*q));
            }
            #pragma unroll
            for (int q = 0; q < 4; ++q) {
                v4f s4 = { sbuf[4*q], sbuf[4*q+1], sbuf[4*q+2], sbuf[4*q+3] };
                __builtin_nontemporal_store(s4, (v4f*)(sout + t + 4*q));
            }
            if (f2 == 0) {
                #pragma unroll
                for (int q = 0; q < 4; ++q) {
                    v4f l4 = { lbuf[4*q], lbuf[4*q+1], lbuf[4*q+2], lbuf[4*q+3] };
                    __builtin_nontemporal_store(l4, (v4f*)(lout + t + 4*q));
                }
            }
        }

        #pragma unroll
        for (int j = 0; j < 8; ++j) prev[j] = cur[8 + j];
    }
}

extern "C" void kernel_launch(void* const* d_in, const int* in_sizes, int n_in,
                              void* d_out, int out_size, void* d_ws, size_t ws_size,
                              hipStream_t stream) {
    const float* x   = (const float*)d_in[0];
    const float* wa  = (const float*)d_in[1];
    const float* wb  = (const float*)d_in[2];
    const float* rta = (const float*)d_in[3];
    const float* rtb = (const float*)d_in[4];
    float* out = (float*)d_out;

    // grid: 32 batch-pairs x 16 chunk-groups = 512 blocks x 256 threads
    snn_kernel<<<dim3(512), dim3(256), 0, stream>>>(x, wa, wb, rta, rtb, out);
}

// Round 6
// 479.670 us; speedup vs baseline: 3.0432x; 3.0432x over previous
//
#include <hip/hip_runtime.h>
#include <math.h>

// SNNEventModel: causal conv (K=8, L2-normalized filters) -> LIF scan.
// B=64, 2 input chans, 16 filters each => 32 output channels, L=16384.
// Outputs (concat flat): v[64*32*L], z[64*32*L], s[64*32*L], logits[64*L].
//
// Round-4 kernel PASSED (f64 trajectory == np reference; absmax 0.125) but
// ran 1140us: WRITE_SIZE showed 2.1x amplification (nt 16B/lane partial-line
// writes) and 64 lines/store-instr at 64KB stride (lane=channel layout).
//
// This round: wave = one (b,f) row, lane = its own 256-step chunk
// (WARM=192 from v=0 -> trajectories BIT-IDENTICAL to round 4). Outputs
// are register-buffered 16 deep, transposed through LDS, and stored as
// FULL 64B lines (16 complete lines per instruction, 1KB stride, one
// contiguous 64KB row per wave). Logits (cross-channel max) moved to a
// small second kernel reading z back (coalesced, ~L3-resident).

#define LSEQ 16384
#define KW 8
#define NB 64
#define CHUNK 256
#define WARM 192
#define ITERS 28        // (WARM + CHUNK) / 16
#define MAIN_ITER 12    // WARM / 16
#define TSTRIDE 20      // floats; 80B row stride: 16B-aligned b128, bank-balanced

typedef float v4f __attribute__((ext_vector_type(4)));

__global__ __launch_bounds__(256, 2)
void snn_scan_kernel(const float* __restrict__ x,
                     const float* __restrict__ wa,
                     const float* __restrict__ wb,
                     const float* __restrict__ rta,
                     const float* __restrict__ rtb,
                     float* __restrict__ out)
{
    __shared__ float lds_v[4][64 * TSTRIDE];
    __shared__ float lds_z[4][64 * TSTRIDE];
    __shared__ float lds_s[4][64 * TSTRIDE];

    const int tid  = threadIdx.x;
    const int lane = tid & 63;
    const int w    = tid >> 6;               // wave within block
    const int wid  = blockIdx.x * 4 + w;     // 0..2047 = (b,f) row id
    const int b    = wid >> 5;
    const int f    = wid & 31;
    const int chan = f >> 4;                 // 0: group a, 1: group b

    // Per-row constants, computed redundantly by all lanes (f64, same as r4).
    const float* wsrc = (chan == 0) ? (wa + f * KW) : (wb + (f - 16) * KW);
    double wn[KW];
    {
        double ss = 0.0;
        #pragma unroll
        for (int k = 0; k < KW; ++k) { double wv = (double)wsrc[k]; ss = fma(wv, wv, ss); }
        double norm = fmax(sqrt(ss), 1e-8);      // clip(sqrt(sum w^2), 1e-8)
        #pragma unroll
        for (int k = 0; k < KW; ++k) wn[k] = (double)wsrc[k] / norm;
    }
    const double rt    = (double)((chan == 0) ? rta[f] : rtb[f - 16]);
    const double sp    = fmax(rt, 0.0) + log1p(exp(-fabs(rt)));  // softplus
    const double tau   = sp + 1e-4;
    const double alpha = exp(-1.0 / tau);        // DT = 1.0
    const double oma   = 1.0 - alpha;

    const float* xp  = x + ((size_t)b * 2 + chan) * LSEQ;
    const size_t NCH = (size_t)NB * 32 * LSEQ;   // 33,554,432
    const size_t row = (size_t)(b * 32 + f) * LSEQ;
    float* vout = out + row;
    float* zout = out + NCH + row;
    float* sout = out + 2 * NCH + row;

    float* Tv = lds_v[w];
    float* Tz = lds_z[w];
    float* Ts = lds_s[w];

    // lane's chunk: main region [lane*256, lane*256+256), warm-up 192 before.
    const int tbase0 = lane * CHUNK - WARM;      // negative only for lane 0

    double prev[8];                              // x[t-8 .. t)
    if (tbase0 >= 8) {                           // lanes >= 1
        v4f p0 = *reinterpret_cast<const v4f*>(xp + tbase0 - 8);
        v4f p1 = *reinterpret_cast<const v4f*>(xp + tbase0 - 4);
        prev[0]=(double)p0[0]; prev[1]=(double)p0[1]; prev[2]=(double)p0[2]; prev[3]=(double)p0[3];
        prev[4]=(double)p1[0]; prev[5]=(double)p1[1]; prev[6]=(double)p1[2]; prev[7]=(double)p1[3];
    } else {                                     // lane 0: causal zero pad
        #pragma unroll
        for (int j = 0; j < 8; ++j) prev[j] = 0.0;
    }

    double v = 0.0;

    for (int iter = 0; iter < ITERS; ++iter) {
        const int t = tbase0 + iter * 16;        // per-lane time
        float vb[16], zb[16], sb[16];

        if (t >= 0) {                            // masks lane 0 during its pre-pad
            v4f c0 = *reinterpret_cast<const v4f*>(xp + t);
            v4f c1 = *reinterpret_cast<const v4f*>(xp + t + 4);
            v4f c2 = *reinterpret_cast<const v4f*>(xp + t + 8);
            v4f c3 = *reinterpret_cast<const v4f*>(xp + t + 12);
            double cur[16] = { (double)c0[0],(double)c0[1],(double)c0[2],(double)c0[3],
                               (double)c1[0],(double)c1[1],(double)c1[2],(double)c1[3],
                               (double)c2[0],(double)c2[1],(double)c2[2],(double)c2[3],
                               (double)c3[0],(double)c3[1],(double)c3[2],(double)c3[3] };
            #pragma unroll
            for (int p = 0; p < 16; ++p) {
                double I = 0.0;
                #pragma unroll
                for (int k = 0; k < KW; ++k) {
                    const int idx = p + k - 7;   // compile-time constant
                    const double xv = (idx < 0) ? prev[8 + idx] : cur[idx];
                    I = fma(wn[k], xv, I);
                }
                const double v_pre = fma(alpha, v, oma * I);
                const double z     = 15.0 * (v_pre - 0.25);
                const bool   spike = (v_pre >= 0.25);
                v = spike ? 0.0 : v_pre;         // v_pre*(1-s_hard), exact
                vb[p] = (float)v_pre;
                zb[p] = (float)z;
                sb[p] = spike ? 1.f : 0.f;       // straight-through fwd == s_hard
            }
            #pragma unroll
            for (int j = 0; j < 8; ++j) prev[j] = cur[8 + j];
        }

        if (iter >= MAIN_ITER) {                 // uniform across the wave
            const int jb = (iter - MAIN_ITER) * 16;   // 0..240, within-chunk base

            // stage lane-major tiles: T[lane][j] = value at t = lane*256+jb+j
            #pragma unroll
            for (int m = 0; m < 4; ++m) {
                v4f vv = { vb[4*m], vb[4*m+1], vb[4*m+2], vb[4*m+3] };
                v4f zz = { zb[4*m], zb[4*m+1], zb[4*m+2], zb[4*m+3] };
                v4f sv = { sb[4*m], sb[4*m+1], sb[4*m+2], sb[4*m+3] };
                *reinterpret_cast<v4f*>(&Tv[lane * TSTRIDE + 4*m]) = vv;
                *reinterpret_cast<v4f*>(&Tz[lane * TSTRIDE + 4*m]) = zz;
                *reinterpret_cast<v4f*>(&Ts[lane * TSTRIDE + 4*m]) = sv;
            }
            // same-wave DS ops execute in order; lgkmcnt handled by compiler.
            // read transposed: lane-quad (lanes 4r..4r+3) emits one FULL 64B
            // line of chunk blk = q*16+r  -> 16 complete lines per instruction.
            #pragma unroll
            for (int q = 0; q < 4; ++q) {
                const int blk = q * 16 + (lane >> 2);
                const int off = blk * TSTRIDE + (lane & 3) * 4;
                const size_t g = (size_t)blk * CHUNK + jb + (lane & 3) * 4;
                v4f vv = *reinterpret_cast<const v4f*>(&Tv[off]);
                v4f zz = *reinterpret_cast<const v4f*>(&Tz[off]);
                v4f sv = *reinterpret_cast<const v4f*>(&Ts[off]);
                __builtin_nontemporal_store(vv, (v4f*)(vout + g));  // never re-read
                *reinterpret_cast<v4f*>(zout + g) = zz;             // re-read by k2
                __builtin_nontemporal_store(sv, (v4f*)(sout + g));  // never re-read
            }
        }
    }
}

// logits[b][t] = max over 32 channels of z[b][ch][t]; fully coalesced.
__global__ __launch_bounds__(256, 4)
void snn_logits_kernel(const float* __restrict__ z, float* __restrict__ lout)
{
    const int b   = blockIdx.x >> 4;             // 64 batches
    const int seg = blockIdx.x & 15;             // 16 segments of 1024
    const int t0  = seg * 1024 + threadIdx.x * 4;
    const float* zp = z + (size_t)b * 32 * LSEQ + t0;

    v4f m = *reinterpret_cast<const v4f*>(zp);
    #pragma unroll
    for (int ch = 1; ch < 32; ++ch) {
        v4f a = *reinterpret_cast<const v4f*>(zp + (size_t)ch * LSEQ);
        m[0] = fmaxf(m[0], a[0]);
        m[1] = fmaxf(m[1], a[1]);
        m[2] = fmaxf(m[2], a[2]);
        m[3] = fmaxf(m[3], a[3]);
    }
    __builtin_nontemporal_store(m, (v4f*)(lout + (size_t)b * LSEQ + t0));
}

extern "C" void kernel_launch(void* const* d_in, const int* in_sizes, int n_in,
                              void* d_out, int out_size, void* d_ws, size_t ws_size,
                              hipStream_t stream) {
    const float* x   = (const float*)d_in[0];
    const float* wa  = (const float*)d_in[1];
    const float* wb  = (const float*)d_in[2];
    const float* rta = (const float*)d_in[3];
    const float* rtb = (const float*)d_in[4];
    float* out = (float*)d_out;

    const size_t NCH = (size_t)NB * 32 * LSEQ;

    // kernel 1: 2048 row-waves = 512 blocks x 4 waves
    snn_scan_kernel<<<dim3(512), dim3(256), 0, stream>>>(x, wa, wb, rta, rtb, out);
    // kernel 2: logits from z (stream-ordered after kernel 1)
    snn_logits_kernel<<<dim3(1024), dim3(256), 0, stream>>>(out + NCH, out + 3 * NCH);
}